// Round 5
// baseline (2378.372 us; speedup 1.0000x reference)
//
#include <hip/hip_runtime.h>

#define NU 500000
#define NI 200000
#define NN (NU + NI)         // combined node count (users then items)
#define NE 2000000
#define HD 32
#define DF 256
#define OC 96                // output row stride = 3*H

typedef float        f4 __attribute__((ext_vector_type(4)));
typedef unsigned int u2 __attribute__((ext_vector_type(2)));
typedef unsigned short ushort_t;

__device__ __forceinline__ float lrelu(float v){ return v >= 0.f ? v : 0.01f*v; }

// f32 -> bf16 round-to-nearest-even
__device__ __forceinline__ unsigned int f2bf(float f){
  unsigned int u = __float_as_uint(f);
  u += 0x7fffu + ((u >> 16) & 1u);
  return u >> 16;
}

__global__ void k_zero_i32(int* __restrict__ p, int n){
  int i = blockIdx.x*blockDim.x + threadIdx.x;
  if (i < n) p[i] = 0;
}

// final_user[:,0:32] = user_emb[user_ids]
__global__ void k_init_user(const int* __restrict__ ids, const float* __restrict__ emb,
                            float* __restrict__ outu){
  int i = blockIdx.x*blockDim.x + threadIdx.x;
  if (i >= NU) return;
  int uid = ids[i];
  const f4* s = (const f4*)(emb + (size_t)uid*HD);
  f4* d = (f4*)(outu + (size_t)i*OC);
  #pragma unroll
  for (int q = 0; q < 8; ++q) {
    f4 v = __builtin_nontemporal_load(s + q);
    __builtin_nontemporal_store(v, d + q);
  }
}

// final_item[:,0:32] = item_emb[product_ids] + feat @ W^T + b
__global__ __launch_bounds__(512) void k_init_item(
    const int* __restrict__ ids, const float* __restrict__ emb,
    const float* __restrict__ feat, const float* __restrict__ W,
    const float* __restrict__ bias, float* __restrict__ outi){
  __shared__ float combo[256*34];
  int t = threadIdx.x;
  int r = t & 255;
  int seg = __builtin_amdgcn_readfirstlane(t >> 8);   // 0 or 1, wave-uniform
  int row = blockIdx.x*256 + r;
  bool valid = row < NI;
  float acc[HD];
  #pragma unroll
  for (int h = 0; h < HD; ++h) acc[h] = 0.f;

  if (valid) {
    const f4* f4p = (const f4*)(feat + (size_t)row*DF + seg*128);
    f4 a0 = __builtin_nontemporal_load(f4p);
    f4 a1 = __builtin_nontemporal_load(f4p + 1);
    for (int k0 = 0; k0 < 128; k0 += 8) {
      f4 n0 = {0,0,0,0}, n1 = {0,0,0,0};
      if (k0 + 8 < 128) {
        n0 = __builtin_nontemporal_load(f4p + (k0>>2) + 2);
        n1 = __builtin_nontemporal_load(f4p + (k0>>2) + 3);
      }
      float fv[8] = {a0.x,a0.y,a0.z,a0.w,a1.x,a1.y,a1.z,a1.w};
      #pragma unroll
      for (int kk = 0; kk < 8; ++kk) {
        #pragma unroll
        for (int h = 0; h < HD; ++h)
          acc[h] += fv[kk]*W[h*DF + seg*128 + k0 + kk];   // scalar (s_load) operand
      }
      a0 = n0; a1 = n1;
    }
  }
  if (seg == 1) {
    float2* c2 = (float2*)(combo + r*34);
    #pragma unroll
    for (int q = 0; q < 16; ++q) c2[q] = make_float2(acc[2*q], acc[2*q+1]);
  }
  __syncthreads();
  if (seg == 0 && valid) {
    const float2* c2 = (const float2*)(combo + r*34);
    #pragma unroll
    for (int q = 0; q < 16; ++q) { float2 v = c2[q]; acc[2*q] += v.x; acc[2*q+1] += v.y; }
    int pid = ids[row];
    const f4* ev = (const f4*)(emb + (size_t)pid*HD);
    const f4* bv = (const f4*)bias;
    f4* dst = (f4*)(outi + (size_t)row*OC);
    #pragma unroll
    for (int q = 0; q < 8; ++q) {
      f4 e = ev[q], b = bv[q];
      f4 o;
      o.x = acc[4*q+0]+e.x+b.x; o.y = acc[4*q+1]+e.y+b.y;
      o.z = acc[4*q+2]+e.z+b.z; o.w = acc[4*q+3]+e.w+b.w;
      __builtin_nontemporal_store(o, dst + q);
    }
  }
}

// degree histogram over combined node ids (users 0..NU-1, items NU..NN-1)
__global__ void k_deg(const int* __restrict__ esrc, const int* __restrict__ edst,
                      int* __restrict__ cnt){
  int e = blockIdx.x*blockDim.x + threadIdx.x;
  if (e >= NE) return;
  int u = __builtin_nontemporal_load(esrc + e);
  int p = __builtin_nontemporal_load(edst + e);
  atomicAdd(cnt + u, 1);
  atomicAdd(cnt + NU + p, 1);
}

// ---- 3-kernel exclusive scan over cnt[NN] -> off[NN] ----
__global__ void k_scan1(const int* __restrict__ cnt, int* __restrict__ off,
                        int* __restrict__ part, int n){
  __shared__ int s[256];
  int t = threadIdx.x, i = blockIdx.x*256 + t;
  int v = (i < n) ? cnt[i] : 0;
  s[t] = v; __syncthreads();
  for (int o = 1; o < 256; o <<= 1) {
    int x = (t >= o) ? s[t-o] : 0;
    __syncthreads(); s[t] += x; __syncthreads();
  }
  if (i < n) off[i] = s[t] - v;
  if (t == 255) part[blockIdx.x] = s[255];
}

__global__ void k_scan2(int* __restrict__ part, int nb){
  __shared__ int s[256];
  __shared__ int carry;
  int t = threadIdx.x;
  if (t == 0) carry = 0;
  __syncthreads();
  for (int c0 = 0; c0 < nb; c0 += 256) {
    int i = c0 + t;
    int v = (i < nb) ? part[i] : 0;
    s[t] = v; __syncthreads();
    for (int o = 1; o < 256; o <<= 1) {
      int x = (t >= o) ? s[t-o] : 0;
      __syncthreads(); s[t] += x; __syncthreads();
    }
    int total = s[255];
    if (i < nb) part[i] = carry + s[t] - v;
    __syncthreads();
    if (t == 0) carry += total;
    __syncthreads();
  }
}

__global__ void k_scan3(int* __restrict__ off, const int* __restrict__ part, int n){
  int i = blockIdx.x*256 + threadIdx.x;
  if (i < n) off[i] += part[blockIdx.x];
}

// scatter edges; optionally write neighbor ids (fallback) and partner slots (fast)
__global__ void k_scatter(const int* __restrict__ esrc, const int* __restrict__ edst,
                          const int* __restrict__ off, int* __restrict__ cur,
                          int* __restrict__ nbr, int* __restrict__ partner){
  int e = blockIdx.x*blockDim.x + threadIdx.x;
  if (e >= NE) return;
  int u = __builtin_nontemporal_load(esrc + e);
  int p = __builtin_nontemporal_load(edst + e);
  int s1 = off[u]      + atomicAdd(cur + u,      1);   // user-side slot [0, NE)
  int s2 = off[NU + p] + atomicAdd(cur + NU + p, 1);   // item-side slot [NE, 2NE)
  if (nbr)     { nbr[s1] = p; nbr[s2] = u; }
  if (partner) { partner[s1] = s2; partner[s2] = s1; }
}

// Phase 1: per SOURCE node (8 lanes, 4 cols each), broadcast its bf16 slice to
// edgeval[partner_slot] for every out-edge. Random access is a fire-and-forget
// NT store; reads are coalesced / L1-resident.
__global__ void k_mat(const float* __restrict__ srcbase, int scol, int n_src, int nodebase,
                      const int* __restrict__ off, const int* __restrict__ cnt,
                      const int* __restrict__ partner, ushort_t* __restrict__ edgeval,
                      int slotbase){
  int tid = blockIdx.x*256 + threadIdx.x;
  int node = tid >> 3;
  if (node >= n_src) return;
  int q = tid & 7;
  int gnode = nodebase + node;
  int deg = cnt[gnode];
  if (deg <= 0) return;
  int start = off[gnode];
  f4 v = __builtin_nontemporal_load((const f4*)(srcbase + (size_t)node*OC + scol) + q);
  u2 pv; pv.x = f2bf(v.x) | (f2bf(v.y) << 16); pv.y = f2bf(v.z) | (f2bf(v.w) << 16);
  u2* ev = (u2*)edgeval + q;
  int j = 0;
  for (; j + 4 <= deg; j += 4) {
    int s0 = __builtin_nontemporal_load(partner + start + j + 0) - slotbase;
    int s1 = __builtin_nontemporal_load(partner + start + j + 1) - slotbase;
    int s2 = __builtin_nontemporal_load(partner + start + j + 2) - slotbase;
    int s3 = __builtin_nontemporal_load(partner + start + j + 3) - slotbase;
    __builtin_nontemporal_store(pv, ev + (size_t)s0*8);
    __builtin_nontemporal_store(pv, ev + (size_t)s1*8);
    __builtin_nontemporal_store(pv, ev + (size_t)s2*8);
    __builtin_nontemporal_store(pv, ev + (size_t)s3*8);
  }
  for (; j < deg; ++j) {
    int s = __builtin_nontemporal_load(partner + start + j) - slotbase;
    __builtin_nontemporal_store(pv, ev + (size_t)s*8);
  }
}

// Phase 2: per DST node (8 lanes), sequential read of its edgeval range,
// mean, fused SAGE matvec + leakyReLU. Fully coalesced streaming.
__global__ void k_aggfin(float* __restrict__ dstbase, int n, int nodebase,
                         const ushort_t* __restrict__ edgeval, int slotbase,
                         int xoff, int outoff,
                         const int* __restrict__ off, const int* __restrict__ cnt,
                         const float* __restrict__ Wl, const float* __restrict__ bl,
                         const float* __restrict__ Wr){
  int tid = blockIdx.x*256 + threadIdx.x;
  int node = tid >> 3;
  if (node >= n) return;
  int q = tid & 7;                 // cols q*4 .. q*4+3
  int gnode = nodebase + node;
  int deg = cnt[gnode];
  int start = off[gnode] - slotbase;

  f4 xv = __builtin_nontemporal_load((const f4*)(dstbase + (size_t)node*OC + xoff) + q);

  const u2* ev = (const u2*)edgeval + q;
  f4 a0 = {0,0,0,0}, a1 = a0, a2 = a0, a3 = a0;
  int j = 0;
  for (; j + 4 <= deg; j += 4) {
    u2 r0 = __builtin_nontemporal_load(ev + (size_t)(start+j+0)*8);
    u2 r1 = __builtin_nontemporal_load(ev + (size_t)(start+j+1)*8);
    u2 r2 = __builtin_nontemporal_load(ev + (size_t)(start+j+2)*8);
    u2 r3 = __builtin_nontemporal_load(ev + (size_t)(start+j+3)*8);
    a0.x += __uint_as_float(r0.x << 16); a0.y += __uint_as_float(r0.x & 0xffff0000u);
    a0.z += __uint_as_float(r0.y << 16); a0.w += __uint_as_float(r0.y & 0xffff0000u);
    a1.x += __uint_as_float(r1.x << 16); a1.y += __uint_as_float(r1.x & 0xffff0000u);
    a1.z += __uint_as_float(r1.y << 16); a1.w += __uint_as_float(r1.y & 0xffff0000u);
    a2.x += __uint_as_float(r2.x << 16); a2.y += __uint_as_float(r2.x & 0xffff0000u);
    a2.z += __uint_as_float(r2.y << 16); a2.w += __uint_as_float(r2.y & 0xffff0000u);
    a3.x += __uint_as_float(r3.x << 16); a3.y += __uint_as_float(r3.x & 0xffff0000u);
    a3.z += __uint_as_float(r3.y << 16); a3.w += __uint_as_float(r3.y & 0xffff0000u);
  }
  for (; j < deg; ++j) {
    u2 r = __builtin_nontemporal_load(ev + (size_t)(start+j)*8);
    a0.x += __uint_as_float(r.x << 16); a0.y += __uint_as_float(r.x & 0xffff0000u);
    a0.z += __uint_as_float(r.y << 16); a0.w += __uint_as_float(r.y & 0xffff0000u);
  }
  a0 += a1 + a2 + a3;
  float inv = 1.f / (float)(deg < 1 ? 1 : deg);
  float m0[4] = {a0.x*inv, a0.y*inv, a0.z*inv, a0.w*inv};
  float x0[4] = {xv.x, xv.y, xv.z, xv.w};

  // allgather 4 -> 32 across the 8-thread group
  bool b1 = (q & 1), b2 = (q & 2), b4 = (q & 4);
  float tm1[8], tx1[8];
  #pragma unroll
  for (int k = 0; k < 4; ++k) {
    float om = __shfl_xor(m0[k], 1), ox = __shfl_xor(x0[k], 1);
    tm1[k]   = b1 ? om    : m0[k];  tx1[k]   = b1 ? ox    : x0[k];
    tm1[k+4] = b1 ? m0[k] : om;     tx1[k+4] = b1 ? x0[k] : ox;
  }
  float tm2[16], tx2[16];
  #pragma unroll
  for (int k = 0; k < 8; ++k) {
    float om = __shfl_xor(tm1[k], 2), ox = __shfl_xor(tx1[k], 2);
    tm2[k]   = b2 ? om     : tm1[k];  tx2[k]   = b2 ? ox     : tx1[k];
    tm2[k+8] = b2 ? tm1[k] : om;      tx2[k+8] = b2 ? tx1[k] : ox;
  }
  float m[32], x[32];
  #pragma unroll
  for (int k = 0; k < 16; ++k) {
    float om = __shfl_xor(tm2[k], 4), ox = __shfl_xor(tx2[k], 4);
    m[k]    = b4 ? om     : tm2[k];  x[k]    = b4 ? ox     : tx2[k];
    m[k+16] = b4 ? tm2[k] : om;      x[k+16] = b4 ? tx2[k] : ox;
  }

  float y[4];
  #pragma unroll
  for (int k = 0; k < 4; ++k) {
    int h = q*4 + k;
    float s = bl[h];
    const f4* wl = (const f4*)(Wl + h*HD);
    const f4* wr = (const f4*)(Wr + h*HD);
    #pragma unroll
    for (int j4 = 0; j4 < 8; ++j4) {
      f4 wv = wl[j4];
      s += m[4*j4+0]*wv.x + m[4*j4+1]*wv.y + m[4*j4+2]*wv.z + m[4*j4+3]*wv.w;
    }
    #pragma unroll
    for (int j4 = 0; j4 < 8; ++j4) {
      f4 wv = wr[j4];
      s += x[4*j4+0]*wv.x + x[4*j4+1]*wv.y + x[4*j4+2]*wv.z + x[4*j4+3]*wv.w;
    }
    y[k] = lrelu(s);
  }
  f4 yo; yo.x = y[0]; yo.y = y[1]; yo.z = y[2]; yo.w = y[3];
  __builtin_nontemporal_store(yo, (f4*)(dstbase + (size_t)node*OC + outoff) + q);
}

// ---- fallback (round-3): f32 CSR pull, needs only nbr ----
__global__ void k_pull_fin(float* __restrict__ dstbase, int n, int nodebase,
                           const float* __restrict__ srcbase, int soff, int xoff, int outoff,
                           const int* __restrict__ off, const int* __restrict__ cnt,
                           const int* __restrict__ nbr,
                           const float* __restrict__ Wl, const float* __restrict__ bl,
                           const float* __restrict__ Wr){
  int tid = blockIdx.x*256 + threadIdx.x;
  int node = tid >> 3;
  if (node >= n) return;
  int q = tid & 7;
  int gnode = nodebase + node;
  int deg = cnt[gnode];
  int start = off[gnode];
  f4 xv = *(const f4*)(dstbase + (size_t)node*OC + xoff + q*4);
  const float* sb = srcbase + soff + q*4;
  f4 a0 = {0,0,0,0}, a1 = a0, a2 = a0, a3 = a0;
  int j = 0;
  for (; j + 4 <= deg; j += 4) {
    int s0 = nbr[start+j+0], s1 = nbr[start+j+1];
    int s2 = nbr[start+j+2], s3 = nbr[start+j+3];
    a0 += *(const f4*)(sb + (size_t)s0*OC);
    a1 += *(const f4*)(sb + (size_t)s1*OC);
    a2 += *(const f4*)(sb + (size_t)s2*OC);
    a3 += *(const f4*)(sb + (size_t)s3*OC);
  }
  for (; j < deg; ++j) a0 += *(const f4*)(sb + (size_t)nbr[start+j]*OC);
  a0 += a1 + a2 + a3;
  float inv = 1.f / (float)(deg < 1 ? 1 : deg);
  float m0[4] = {a0.x*inv, a0.y*inv, a0.z*inv, a0.w*inv};
  float x0[4] = {xv.x, xv.y, xv.z, xv.w};
  bool b1 = (q & 1), b2 = (q & 2), b4 = (q & 4);
  float tm1[8], tx1[8];
  #pragma unroll
  for (int k = 0; k < 4; ++k) {
    float om = __shfl_xor(m0[k], 1), ox = __shfl_xor(x0[k], 1);
    tm1[k]   = b1 ? om    : m0[k];  tx1[k]   = b1 ? ox    : x0[k];
    tm1[k+4] = b1 ? m0[k] : om;     tx1[k+4] = b1 ? x0[k] : ox;
  }
  float tm2[16], tx2[16];
  #pragma unroll
  for (int k = 0; k < 8; ++k) {
    float om = __shfl_xor(tm1[k], 2), ox = __shfl_xor(tx1[k], 2);
    tm2[k]   = b2 ? om     : tm1[k];  tx2[k]   = b2 ? ox     : tx1[k];
    tm2[k+8] = b2 ? tm1[k] : om;      tx2[k+8] = b2 ? tx1[k] : ox;
  }
  float m[32], x[32];
  #pragma unroll
  for (int k = 0; k < 16; ++k) {
    float om = __shfl_xor(tm2[k], 4), ox = __shfl_xor(tx2[k], 4);
    m[k]    = b4 ? om     : tm2[k];  x[k]    = b4 ? ox     : tx2[k];
    m[k+16] = b4 ? tm2[k] : om;      x[k+16] = b4 ? tx2[k] : ox;
  }
  float y[4];
  #pragma unroll
  for (int k = 0; k < 4; ++k) {
    int h = q*4 + k;
    float s = bl[h];
    const f4* wl = (const f4*)(Wl + h*HD);
    const f4* wr = (const f4*)(Wr + h*HD);
    #pragma unroll
    for (int j4 = 0; j4 < 8; ++j4) {
      f4 wv = wl[j4];
      s += m[4*j4+0]*wv.x + m[4*j4+1]*wv.y + m[4*j4+2]*wv.z + m[4*j4+3]*wv.w;
    }
    #pragma unroll
    for (int j4 = 0; j4 < 8; ++j4) {
      f4 wv = wr[j4];
      s += x[4*j4+0]*wv.x + x[4*j4+1]*wv.y + x[4*j4+2]*wv.z + x[4*j4+3]*wv.w;
    }
    y[k] = lrelu(s);
  }
  f4 yo; yo.x = y[0]; yo.y = y[1]; yo.z = y[2]; yo.w = y[3];
  *((f4*)(dstbase + (size_t)node*OC + outoff) + q) = yo;
}

extern "C" void kernel_launch(void* const* d_in, const int* in_sizes, int n_in,
                              void* d_out, int out_size, void* d_ws, size_t ws_size,
                              hipStream_t stream) {
  const int*   user_ids = (const int*)d_in[0];
  const int*   prod_ids = (const int*)d_in[1];
  const float* feat     = (const float*)d_in[2];
  const int*   er       = (const int*)d_in[3];   // [2, NE]: row0 = user, row1 = item
  const float* uemb     = (const float*)d_in[5];
  const float* iemb     = (const float*)d_in[6];
  const float* fW       = (const float*)d_in[7];
  const float* fb       = (const float*)d_in[8];
  const float* Wl_up1 = (const float*)d_in[9];
  const float* bl_up1 = (const float*)d_in[10];
  const float* Wr_up1 = (const float*)d_in[11];
  const float* Wl_pu1 = (const float*)d_in[12];
  const float* bl_pu1 = (const float*)d_in[13];
  const float* Wr_pu1 = (const float*)d_in[14];
  const float* Wl_up2 = (const float*)d_in[15];
  const float* bl_up2 = (const float*)d_in[16];
  const float* Wr_up2 = (const float*)d_in[17];
  const float* Wl_pu2 = (const float*)d_in[18];
  const float* bl_pu2 = (const float*)d_in[19];
  const float* Wr_pu2 = (const float*)d_in[20];

  float* outu = (float*)d_out;
  float* outi = outu + (size_t)NU*OC;

  // ws layout (ints): cnt[NN] | cur[NN] | off[NN] | part[2736] | partner-or-nbr[2*NE]
  // fast path additionally: edgeval bf16, NE rows x 64 B (256-aligned)
  int* cnt  = (int*)d_ws;
  int* cur  = cnt + NN;
  int* off  = cur + NN;
  int* part = off + NN;
  int* pn   = part + 2736;            // partner (fast) or nbr (fallback)
  size_t base_bytes = ((size_t)3*NN + 2736 + 2*(size_t)NE) * 4;
  size_t ev_off = (base_bytes + 255) & ~(size_t)255;
  size_t fast_need = ev_off + (size_t)NE * 64;
  bool fast = ws_size >= fast_need;
  ushort_t* edgeval = (ushort_t*)((char*)d_ws + ev_off);

  const int* er_src = er;        // users
  const int* er_dst = er + NE;   // items

  const int B = 256;
  const int NB1 = (NN + 255)/256;

  k_zero_i32<<<(2*NN + B - 1)/B, B, 0, stream>>>(cnt, 2*NN);
  k_deg<<<(NE + B - 1)/B, B, 0, stream>>>(er_src, er_dst, cnt);
  k_scan1<<<NB1, B, 0, stream>>>(cnt, off, part, NN);
  k_scan2<<<1, B, 0, stream>>>(part, NB1);
  k_scan3<<<NB1, B, 0, stream>>>(off, part, NN);
  k_scatter<<<(NE + B - 1)/B, B, 0, stream>>>(er_src, er_dst, off, cur,
                                              fast ? (int*)nullptr : pn,
                                              fast ? pn : (int*)nullptr);

  k_init_user<<<(NU + B - 1)/B, B, 0, stream>>>(user_ids, uemb, outu);
  k_init_item<<<(NI + 255)/256, 512, 0, stream>>>(prod_ids, iemb, feat, fW, fb, outi);

  if (fast) {
    const int GU = ((size_t)NU*8 + B - 1)/B, GI = ((size_t)NI*8 + B - 1)/B;
    // layer 1: items <- users (xu)
    k_mat<<<GU, B, 0, stream>>>(outu, 0, NU, 0, off, cnt, pn, edgeval, NE);
    k_aggfin<<<GI, B, 0, stream>>>(outi, NI, NU, edgeval, NE, 0, 32, off, cnt,
                                   Wl_up1, bl_up1, Wr_up1);
    // layer 1: users <- items (xp)
    k_mat<<<GI, B, 0, stream>>>(outi, 0, NI, NU, off, cnt, pn, edgeval, 0);
    k_aggfin<<<GU, B, 0, stream>>>(outu, NU, 0, edgeval, 0, 0, 32, off, cnt,
                                   Wl_pu1, bl_pu1, Wr_pu1);
    // layer 2: items <- u1
    k_mat<<<GU, B, 0, stream>>>(outu, 32, NU, 0, off, cnt, pn, edgeval, NE);
    k_aggfin<<<GI, B, 0, stream>>>(outi, NI, NU, edgeval, NE, 32, 64, off, cnt,
                                   Wl_up2, bl_up2, Wr_up2);
    // layer 2: users <- p1
    k_mat<<<GI, B, 0, stream>>>(outi, 32, NI, NU, off, cnt, pn, edgeval, 0);
    k_aggfin<<<GU, B, 0, stream>>>(outu, NU, 0, edgeval, 0, 32, 64, off, cnt,
                                   Wl_pu2, bl_pu2, Wr_pu2);
  } else {
    const int GU = ((size_t)NU*8 + B - 1)/B, GI = ((size_t)NI*8 + B - 1)/B;
    k_pull_fin<<<GI, B, 0, stream>>>(outi, NI, NU, outu, 0, 0, 32, off, cnt, pn,
                                     Wl_up1, bl_up1, Wr_up1);
    k_pull_fin<<<GU, B, 0, stream>>>(outu, NU, 0, outi, 0, 0, 32, off, cnt, pn,
                                     Wl_pu1, bl_pu1, Wr_pu1);
    k_pull_fin<<<GI, B, 0, stream>>>(outi, NI, NU, outu, 32, 32, 64, off, cnt, pn,
                                     Wl_up2, bl_up2, Wr_up2);
    k_pull_fin<<<GU, B, 0, stream>>>(outu, NU, 0, outi, 32, 32, 64, off, cnt, pn,
                                     Wl_pu2, bl_pu2, Wr_pu2);
  }
}

// Round 6
// 1764.041 us; speedup vs baseline: 1.3483x; 1.3483x over previous
//
#include <hip/hip_runtime.h>

#define NU 500000
#define NI 200000
#define NN (NU + NI)         // combined node count (users then items)
#define NE 2000000
#define HD 32
#define DF 256
#define OC 96                // output row stride = 3*H

typedef float        f4 __attribute__((ext_vector_type(4)));
typedef unsigned int u2 __attribute__((ext_vector_type(2)));
typedef unsigned int u4v __attribute__((ext_vector_type(4)));
typedef unsigned short ushort_t;

__device__ __forceinline__ float lrelu(float v){ return v >= 0.f ? v : 0.01f*v; }

// f32 -> bf16 round-to-nearest-even
__device__ __forceinline__ unsigned int f2bf(float f){
  unsigned int u = __float_as_uint(f);
  u += 0x7fffu + ((u >> 16) & 1u);
  return u >> 16;
}
__device__ __forceinline__ float bflo(unsigned int u){ return __uint_as_float(u << 16); }
__device__ __forceinline__ float bfhi(unsigned int u){ return __uint_as_float(u & 0xffff0000u); }

__global__ void k_zero_i32(int* __restrict__ p, int n){
  int i = blockIdx.x*blockDim.x + threadIdx.x;
  if (i < n) p[i] = 0;
}

// final_user[:,0:32] = user_emb[user_ids]
__global__ void k_init_user(const int* __restrict__ ids, const float* __restrict__ emb,
                            float* __restrict__ outu){
  int i = blockIdx.x*blockDim.x + threadIdx.x;
  if (i >= NU) return;
  int uid = ids[i];
  const f4* s = (const f4*)(emb + (size_t)uid*HD);
  f4* d = (f4*)(outu + (size_t)i*OC);
  #pragma unroll
  for (int q = 0; q < 8; ++q) {
    f4 v = __builtin_nontemporal_load(s + q);
    __builtin_nontemporal_store(v, d + q);
  }
}

// final_item[:,0:32] = item_emb[product_ids] + feat @ W^T + b   (split-K, 512 thr)
__global__ __launch_bounds__(512) void k_init_item(
    const int* __restrict__ ids, const float* __restrict__ emb,
    const float* __restrict__ feat, const float* __restrict__ W,
    const float* __restrict__ bias, float* __restrict__ outi){
  __shared__ float combo[256*34];
  int t = threadIdx.x;
  int r = t & 255;
  int seg = __builtin_amdgcn_readfirstlane(t >> 8);   // 0 or 1, wave-uniform
  int row = blockIdx.x*256 + r;
  bool valid = row < NI;
  float acc[HD];
  #pragma unroll
  for (int h = 0; h < HD; ++h) acc[h] = 0.f;

  if (valid) {
    const f4* f4p = (const f4*)(feat + (size_t)row*DF + seg*128);
    f4 a0 = __builtin_nontemporal_load(f4p);
    f4 a1 = __builtin_nontemporal_load(f4p + 1);
    for (int k0 = 0; k0 < 128; k0 += 8) {
      f4 n0 = {0,0,0,0}, n1 = {0,0,0,0};
      if (k0 + 8 < 128) {
        n0 = __builtin_nontemporal_load(f4p + (k0>>2) + 2);
        n1 = __builtin_nontemporal_load(f4p + (k0>>2) + 3);
      }
      float fv[8] = {a0.x,a0.y,a0.z,a0.w,a1.x,a1.y,a1.z,a1.w};
      #pragma unroll
      for (int kk = 0; kk < 8; ++kk) {
        #pragma unroll
        for (int h = 0; h < HD; ++h)
          acc[h] += fv[kk]*W[h*DF + seg*128 + k0 + kk];   // scalar (s_load) operand
      }
      a0 = n0; a1 = n1;
    }
  }
  if (seg == 1) {
    float2* c2 = (float2*)(combo + r*34);
    #pragma unroll
    for (int q = 0; q < 16; ++q) c2[q] = make_float2(acc[2*q], acc[2*q+1]);
  }
  __syncthreads();
  if (seg == 0 && valid) {
    const float2* c2 = (const float2*)(combo + r*34);
    #pragma unroll
    for (int q = 0; q < 16; ++q) { float2 v = c2[q]; acc[2*q] += v.x; acc[2*q+1] += v.y; }
    int pid = ids[row];
    const f4* ev = (const f4*)(emb + (size_t)pid*HD);
    const f4* bv = (const f4*)bias;
    f4* dst = (f4*)(outi + (size_t)row*OC);
    #pragma unroll
    for (int q = 0; q < 8; ++q) {
      f4 e = ev[q], b = bv[q];
      f4 o;
      o.x = acc[4*q+0]+e.x+b.x; o.y = acc[4*q+1]+e.y+b.y;
      o.z = acc[4*q+2]+e.z+b.z; o.w = acc[4*q+3]+e.w+b.w;
      __builtin_nontemporal_store(o, dst + q);
    }
  }
}

// degree histogram over combined node ids
__global__ void k_deg(const int* __restrict__ esrc, const int* __restrict__ edst,
                      int* __restrict__ cnt){
  int e = blockIdx.x*blockDim.x + threadIdx.x;
  if (e >= NE) return;
  int u = __builtin_nontemporal_load(esrc + e);
  int p = __builtin_nontemporal_load(edst + e);
  atomicAdd(cnt + u, 1);
  atomicAdd(cnt + NU + p, 1);
}

// ---- 3-kernel exclusive scan over cnt[NN] -> off[NN] ----
__global__ void k_scan1(const int* __restrict__ cnt, int* __restrict__ off,
                        int* __restrict__ part, int n){
  __shared__ int s[256];
  int t = threadIdx.x, i = blockIdx.x*256 + t;
  int v = (i < n) ? cnt[i] : 0;
  s[t] = v; __syncthreads();
  for (int o = 1; o < 256; o <<= 1) {
    int x = (t >= o) ? s[t-o] : 0;
    __syncthreads(); s[t] += x; __syncthreads();
  }
  if (i < n) off[i] = s[t] - v;
  if (t == 255) part[blockIdx.x] = s[255];
}

__global__ void k_scan2(int* __restrict__ part, int nb){
  __shared__ int s[256];
  __shared__ int carry;
  int t = threadIdx.x;
  if (t == 0) carry = 0;
  __syncthreads();
  for (int c0 = 0; c0 < nb; c0 += 256) {
    int i = c0 + t;
    int v = (i < nb) ? part[i] : 0;
    s[t] = v; __syncthreads();
    for (int o = 1; o < 256; o <<= 1) {
      int x = (t >= o) ? s[t-o] : 0;
      __syncthreads(); s[t] += x; __syncthreads();
    }
    int total = s[255];
    if (i < nb) part[i] = carry + s[t] - v;
    __syncthreads();
    if (t == 0) carry += total;
    __syncthreads();
  }
}

__global__ void k_scan3(int* __restrict__ off, const int* __restrict__ part, int n){
  int i = blockIdx.x*256 + threadIdx.x;
  if (i < n) off[i] += part[blockIdx.x];
}

// scatter edges -> partner slots (user slot [0,NE), item slot [NE,2NE))
__global__ void k_scatter(const int* __restrict__ esrc, const int* __restrict__ edst,
                          const int* __restrict__ off, int* __restrict__ cur,
                          int* __restrict__ partner){
  int e = blockIdx.x*blockDim.x + threadIdx.x;
  if (e >= NE) return;
  int u = __builtin_nontemporal_load(esrc + e);
  int p = __builtin_nontemporal_load(edst + e);
  int s1 = off[u]      + atomicAdd(cur + u,      1);
  int s2 = off[NU + p] + atomicAdd(cur + NU + p, 1);
  partner[s1] = s2;
  partner[s2] = s1;
}

// Phase 1: per SOURCE node (8 lanes, 4 cols each), broadcast bf16 slice to
// edgeval[partner_slot] for every out-edge (fire-and-forget NT stores).
__global__ void k_mat(const float* __restrict__ srcbase, int scol, int n_src, int nodebase,
                      const int* __restrict__ off, const int* __restrict__ cnt,
                      const int* __restrict__ partner, ushort_t* __restrict__ edgeval,
                      int slotbase){
  int tid = blockIdx.x*256 + threadIdx.x;
  int node = tid >> 3;
  if (node >= n_src) return;
  int q = tid & 7;
  int gnode = nodebase + node;
  int deg = cnt[gnode];
  if (deg <= 0) return;
  int start = off[gnode];
  f4 v = __builtin_nontemporal_load((const f4*)(srcbase + (size_t)node*OC + scol) + q);
  u2 pv; pv.x = f2bf(v.x) | (f2bf(v.y) << 16); pv.y = f2bf(v.z) | (f2bf(v.w) << 16);
  u2* ev = (u2*)edgeval + q;
  int j = 0;
  for (; j + 4 <= deg; j += 4) {
    int s0 = __builtin_nontemporal_load(partner + start + j + 0) - slotbase;
    int s1 = __builtin_nontemporal_load(partner + start + j + 1) - slotbase;
    int s2 = __builtin_nontemporal_load(partner + start + j + 2) - slotbase;
    int s3 = __builtin_nontemporal_load(partner + start + j + 3) - slotbase;
    __builtin_nontemporal_store(pv, ev + (size_t)s0*8);
    __builtin_nontemporal_store(pv, ev + (size_t)s1*8);
    __builtin_nontemporal_store(pv, ev + (size_t)s2*8);
    __builtin_nontemporal_store(pv, ev + (size_t)s3*8);
  }
  for (; j < deg; ++j) {
    int s = __builtin_nontemporal_load(partner + start + j) - slotbase;
    __builtin_nontemporal_store(pv, ev + (size_t)s*8);
  }
}

// Phase 2a (NEW): per DST node (8 lanes), sequential segmented MEAN only.
// No shuffles, no matvec, no NT — minimal register pressure. Writes bf16 mean row.
__global__ void k_aggsum(const ushort_t* __restrict__ edgeval, int slotbase,
                         int n, int nodebase,
                         const int* __restrict__ off, const int* __restrict__ cnt,
                         ushort_t* __restrict__ meanb){
  int tid = blockIdx.x*256 + threadIdx.x;
  int node = tid >> 3;
  if (node >= n) return;
  int q = tid & 7;
  int gnode = nodebase + node;
  int deg = cnt[gnode];
  int start = off[gnode] - slotbase;
  const u2* ev = (const u2*)edgeval + q;
  f4 a0 = {0,0,0,0}, a1 = a0, a2 = a0, a3 = a0;
  int j = 0;
  for (; j + 4 <= deg; j += 4) {
    u2 r0 = ev[(size_t)(start+j+0)*8];
    u2 r1 = ev[(size_t)(start+j+1)*8];
    u2 r2 = ev[(size_t)(start+j+2)*8];
    u2 r3 = ev[(size_t)(start+j+3)*8];
    a0.x += bflo(r0.x); a0.y += bfhi(r0.x); a0.z += bflo(r0.y); a0.w += bfhi(r0.y);
    a1.x += bflo(r1.x); a1.y += bfhi(r1.x); a1.z += bflo(r1.y); a1.w += bfhi(r1.y);
    a2.x += bflo(r2.x); a2.y += bfhi(r2.x); a2.z += bflo(r2.y); a2.w += bfhi(r2.y);
    a3.x += bflo(r3.x); a3.y += bfhi(r3.x); a3.z += bflo(r3.y); a3.w += bfhi(r3.y);
  }
  for (; j < deg; ++j) {
    u2 r = ev[(size_t)(start+j)*8];
    a0.x += bflo(r.x); a0.y += bfhi(r.x); a0.z += bflo(r.y); a0.w += bfhi(r.y);
  }
  a0 += a1 + a2 + a3;
  float inv = (deg > 0) ? 1.f/(float)deg : 0.f;
  u2 pv;
  pv.x = f2bf(a0.x*inv) | (f2bf(a0.y*inv) << 16);
  pv.y = f2bf(a0.z*inv) | (f2bf(a0.w*inv) << 16);
  *((u2*)meanb + (size_t)node*8 + q) = pv;
}

// Phase 2b (NEW): thread-per-node fused SAGE linear + leakyReLU, scalar-W FMAs.
__global__ void k_fin2(float* __restrict__ dstbase, int n,
                       const ushort_t* __restrict__ meanb, int xoff, int outoff,
                       const float* __restrict__ Wl, const float* __restrict__ bl,
                       const float* __restrict__ Wr){
  int i = blockIdx.x*blockDim.x + threadIdx.x;
  if (i >= n) return;
  float m[HD], x[HD];
  const u4v* mb = (const u4v*)(meanb + (size_t)i*HD);
  #pragma unroll
  for (int t = 0; t < 4; ++t) {
    u4v v = mb[t];
    m[8*t+0] = bflo(v.x); m[8*t+1] = bfhi(v.x);
    m[8*t+2] = bflo(v.y); m[8*t+3] = bfhi(v.y);
    m[8*t+4] = bflo(v.z); m[8*t+5] = bfhi(v.z);
    m[8*t+6] = bflo(v.w); m[8*t+7] = bfhi(v.w);
  }
  float* row = dstbase + (size_t)i*OC;
  #pragma unroll
  for (int qq = 0; qq < 8; ++qq) {
    f4 xx = *((const f4*)(row + xoff) + qq);
    x[4*qq+0]=xx.x; x[4*qq+1]=xx.y; x[4*qq+2]=xx.z; x[4*qq+3]=xx.w;
  }
  float y[HD];
  #pragma unroll
  for (int h = 0; h < HD; ++h) {
    float s = bl[h];
    #pragma unroll
    for (int j = 0; j < HD; ++j) s += m[j]*Wl[h*HD+j];   // W uniform -> s_load
    #pragma unroll
    for (int j = 0; j < HD; ++j) s += x[j]*Wr[h*HD+j];
    y[h] = lrelu(s);
  }
  #pragma unroll
  for (int qq = 0; qq < 8; ++qq) {
    f4 yo; yo.x=y[4*qq+0]; yo.y=y[4*qq+1]; yo.z=y[4*qq+2]; yo.w=y[4*qq+3];
    __builtin_nontemporal_store(yo, (f4*)(row + outoff) + qq);
  }
}

// Fallback (round-5 fused aggfin) — only used if ws too small for mean buffer.
__global__ void k_aggfin(float* __restrict__ dstbase, int n, int nodebase,
                         const ushort_t* __restrict__ edgeval, int slotbase,
                         int xoff, int outoff,
                         const int* __restrict__ off, const int* __restrict__ cnt,
                         const float* __restrict__ Wl, const float* __restrict__ bl,
                         const float* __restrict__ Wr){
  int tid = blockIdx.x*256 + threadIdx.x;
  int node = tid >> 3;
  if (node >= n) return;
  int q = tid & 7;
  int gnode = nodebase + node;
  int deg = cnt[gnode];
  int start = off[gnode] - slotbase;
  f4 xv = *((const f4*)(dstbase + (size_t)node*OC + xoff) + q);
  const u2* ev = (const u2*)edgeval + q;
  f4 a0 = {0,0,0,0};
  for (int j = 0; j < deg; ++j) {
    u2 r = ev[(size_t)(start+j)*8];
    a0.x += bflo(r.x); a0.y += bfhi(r.x); a0.z += bflo(r.y); a0.w += bfhi(r.y);
  }
  float inv = (deg > 0) ? 1.f/(float)deg : 0.f;
  float m0[4] = {a0.x*inv, a0.y*inv, a0.z*inv, a0.w*inv};
  float x0[4] = {xv.x, xv.y, xv.z, xv.w};
  bool b1 = (q & 1), b2 = (q & 2), b4 = (q & 4);
  float tm1[8], tx1[8];
  #pragma unroll
  for (int k = 0; k < 4; ++k) {
    float om = __shfl_xor(m0[k], 1), ox = __shfl_xor(x0[k], 1);
    tm1[k]   = b1 ? om    : m0[k];  tx1[k]   = b1 ? ox    : x0[k];
    tm1[k+4] = b1 ? m0[k] : om;     tx1[k+4] = b1 ? x0[k] : ox;
  }
  float tm2[16], tx2[16];
  #pragma unroll
  for (int k = 0; k < 8; ++k) {
    float om = __shfl_xor(tm1[k], 2), ox = __shfl_xor(tx1[k], 2);
    tm2[k]   = b2 ? om     : tm1[k];  tx2[k]   = b2 ? ox     : tx1[k];
    tm2[k+8] = b2 ? tm1[k] : om;      tx2[k+8] = b2 ? tx1[k] : ox;
  }
  float m[32], x[32];
  #pragma unroll
  for (int k = 0; k < 16; ++k) {
    float om = __shfl_xor(tm2[k], 4), ox = __shfl_xor(tx2[k], 4);
    m[k]    = b4 ? om     : tm2[k];  x[k]    = b4 ? ox     : tx2[k];
    m[k+16] = b4 ? tm2[k] : om;      x[k+16] = b4 ? tx2[k] : ox;
  }
  float y[4];
  #pragma unroll
  for (int k = 0; k < 4; ++k) {
    int h = q*4 + k;
    float s = bl[h];
    const f4* wl = (const f4*)(Wl + h*HD);
    const f4* wr = (const f4*)(Wr + h*HD);
    #pragma unroll
    for (int j4 = 0; j4 < 8; ++j4) {
      f4 wv = wl[j4];
      s += m[4*j4+0]*wv.x + m[4*j4+1]*wv.y + m[4*j4+2]*wv.z + m[4*j4+3]*wv.w;
    }
    #pragma unroll
    for (int j4 = 0; j4 < 8; ++j4) {
      f4 wv = wr[j4];
      s += x[4*j4+0]*wv.x + x[4*j4+1]*wv.y + x[4*j4+2]*wv.z + x[4*j4+3]*wv.w;
    }
    y[k] = lrelu(s);
  }
  f4 yo; yo.x = y[0]; yo.y = y[1]; yo.z = y[2]; yo.w = y[3];
  *((f4*)(dstbase + (size_t)node*OC + outoff) + q) = yo;
}

extern "C" void kernel_launch(void* const* d_in, const int* in_sizes, int n_in,
                              void* d_out, int out_size, void* d_ws, size_t ws_size,
                              hipStream_t stream) {
  const int*   user_ids = (const int*)d_in[0];
  const int*   prod_ids = (const int*)d_in[1];
  const float* feat     = (const float*)d_in[2];
  const int*   er       = (const int*)d_in[3];   // [2, NE]: row0 = user, row1 = item
  const float* uemb     = (const float*)d_in[5];
  const float* iemb     = (const float*)d_in[6];
  const float* fW       = (const float*)d_in[7];
  const float* fb       = (const float*)d_in[8];
  const float* Wl_up1 = (const float*)d_in[9];
  const float* bl_up1 = (const float*)d_in[10];
  const float* Wr_up1 = (const float*)d_in[11];
  const float* Wl_pu1 = (const float*)d_in[12];
  const float* bl_pu1 = (const float*)d_in[13];
  const float* Wr_pu1 = (const float*)d_in[14];
  const float* Wl_up2 = (const float*)d_in[15];
  const float* bl_up2 = (const float*)d_in[16];
  const float* Wr_up2 = (const float*)d_in[17];
  const float* Wl_pu2 = (const float*)d_in[18];
  const float* bl_pu2 = (const float*)d_in[19];
  const float* Wr_pu2 = (const float*)d_in[20];

  float* outu = (float*)d_out;
  float* outi = outu + (size_t)NU*OC;

  // ws: ints cnt[NN]|cur[NN]|off[NN]|part[2736]|partner[2NE], then
  // edgeval (NE x 64 B, 256-aligned), then meanb (NU x 64 B bf16)
  int* cnt  = (int*)d_ws;
  int* cur  = cnt + NN;
  int* off  = cur + NN;
  int* part = off + NN;
  int* pn   = part + 2736;
  size_t base_bytes = ((size_t)3*NN + 2736 + 2*(size_t)NE) * 4;
  size_t ev_off = (base_bytes + 255) & ~(size_t)255;
  ushort_t* edgeval = (ushort_t*)((char*)d_ws + ev_off);
  size_t mb_off = ev_off + (size_t)NE*64;
  ushort_t* meanb = (ushort_t*)((char*)d_ws + mb_off);
  bool have_mean = ws_size >= mb_off + (size_t)NU*64;

  const int* er_src = er;        // users
  const int* er_dst = er + NE;   // items

  const int B = 256;
  const int NB1 = (NN + 255)/256;
  const int GU8 = ((size_t)NU*8 + B - 1)/B, GI8 = ((size_t)NI*8 + B - 1)/B;
  const int GU1 = (NU + B - 1)/B,           GI1 = (NI + B - 1)/B;

  k_zero_i32<<<(2*NN + B - 1)/B, B, 0, stream>>>(cnt, 2*NN);
  k_deg<<<(NE + B - 1)/B, B, 0, stream>>>(er_src, er_dst, cnt);
  k_scan1<<<NB1, B, 0, stream>>>(cnt, off, part, NN);
  k_scan2<<<1, B, 0, stream>>>(part, NB1);
  k_scan3<<<NB1, B, 0, stream>>>(off, part, NN);
  k_scatter<<<(NE + B - 1)/B, B, 0, stream>>>(er_src, er_dst, off, cur, pn);

  k_init_user<<<GU1, B, 0, stream>>>(user_ids, uemb, outu);
  k_init_item<<<(NI + 255)/256, 512, 0, stream>>>(prod_ids, iemb, feat, fW, fb, outi);

  if (have_mean) {
    // layer 1: items <- users (xu)
    k_mat<<<GU8, B, 0, stream>>>(outu, 0, NU, 0, off, cnt, pn, edgeval, NE);
    k_aggsum<<<GI8, B, 0, stream>>>(edgeval, NE, NI, NU, off, cnt, meanb);
    k_fin2<<<GI1, B, 0, stream>>>(outi, NI, meanb, 0, 32, Wl_up1, bl_up1, Wr_up1);
    // layer 1: users <- items (xp)
    k_mat<<<GI8, B, 0, stream>>>(outi, 0, NI, NU, off, cnt, pn, edgeval, 0);
    k_aggsum<<<GU8, B, 0, stream>>>(edgeval, 0, NU, 0, off, cnt, meanb);
    k_fin2<<<GU1, B, 0, stream>>>(outu, NU, meanb, 0, 32, Wl_pu1, bl_pu1, Wr_pu1);
    // layer 2: items <- u1
    k_mat<<<GU8, B, 0, stream>>>(outu, 32, NU, 0, off, cnt, pn, edgeval, NE);
    k_aggsum<<<GI8, B, 0, stream>>>(edgeval, NE, NI, NU, off, cnt, meanb);
    k_fin2<<<GI1, B, 0, stream>>>(outi, NI, meanb, 32, 64, Wl_up2, bl_up2, Wr_up2);
    // layer 2: users <- p1
    k_mat<<<GI8, B, 0, stream>>>(outi, 32, NI, NU, off, cnt, pn, edgeval, 0);
    k_aggsum<<<GU8, B, 0, stream>>>(edgeval, 0, NU, 0, off, cnt, meanb);
    k_fin2<<<GU1, B, 0, stream>>>(outu, NU, meanb, 32, 64, Wl_pu2, bl_pu2, Wr_pu2);
  } else {
    k_mat<<<GU8, B, 0, stream>>>(outu, 0, NU, 0, off, cnt, pn, edgeval, NE);
    k_aggfin<<<GI8, B, 0, stream>>>(outi, NI, NU, edgeval, NE, 0, 32, off, cnt,
                                    Wl_up1, bl_up1, Wr_up1);
    k_mat<<<GI8, B, 0, stream>>>(outi, 0, NI, NU, off, cnt, pn, edgeval, 0);
    k_aggfin<<<GU8, B, 0, stream>>>(outu, NU, 0, edgeval, 0, 0, 32, off, cnt,
                                    Wl_pu1, bl_pu1, Wr_pu1);
    k_mat<<<GU8, B, 0, stream>>>(outu, 32, NU, 0, off, cnt, pn, edgeval, NE);
    k_aggfin<<<GI8, B, 0, stream>>>(outi, NI, NU, edgeval, NE, 32, 64, off, cnt,
                                    Wl_up2, bl_up2, Wr_up2);
    k_mat<<<GI8, B, 0, stream>>>(outi, 32, NI, NU, off, cnt, pn, edgeval, 0);
    k_aggfin<<<GU8, B, 0, stream>>>(outu, NU, 0, edgeval, 0, 32, 64, off, cnt,
                                    Wl_pu2, bl_pu2, Wr_pu2);
  }
}